// Round 5
// baseline (491.525 us; speedup 1.0000x reference)
//
#include <hip/hip_runtime.h>

typedef _Float16 f16;
typedef _Float16 f16x2 __attribute__((ext_vector_type(2)));
typedef _Float16 f16x4 __attribute__((ext_vector_type(4)));
typedef _Float16 f16x8 __attribute__((ext_vector_type(8)));
typedef __fp16 h16x2 __attribute__((ext_vector_type(2)));
typedef float f32x4 __attribute__((ext_vector_type(4)));
typedef float fltx4 __attribute__((ext_vector_type(4)));

#define NB 65536

// Pre-transposed f16 weights: [m][out_col][k], m: 0=Wq 1=Wk 2=Wv 3=Wo
__device__ __align__(16) f16 g_WT[4][128][128];

__global__ void k_wtrans(const float* __restrict__ Wq, const float* __restrict__ Wk,
                         const float* __restrict__ Wv, const float* __restrict__ Wo) {
    int tid = blockIdx.x * 256 + threadIdx.x;   // 65536 threads
    int m = tid >> 14;
    int r = tid & 16383;
    int n = r >> 7;          // output column
    int k = r & 127;         // K index
    const float* W = (m == 0) ? Wq : (m == 1) ? Wk : (m == 2) ? Wv : Wo;
    g_WT[m][n][k] = (f16)W[k * 128 + n];
}

__device__ __forceinline__ f16x2 bc2(unsigned u) {
    union { unsigned u; f16x2 h; } x; x.u = u; return x.h;
}
__device__ __forceinline__ f16x2 pkh(float a, float b) {
    union { h16x2 a; f16x2 b; } u;
    u.a = __builtin_amdgcn_cvt_pkrtz(a, b);
    return u.b;
}
__device__ __forceinline__ f16x8 cat8(f16x4 lo, f16x4 hi) {
    f16x8 r;
    r[0] = lo[0]; r[1] = lo[1]; r[2] = lo[2]; r[3] = lo[3];
    r[4] = hi[0]; r[5] = hi[1]; r[6] = hi[2]; r[7] = hi[3];
    return r;
}

// 8 waves per block; wave w owns head w for 16 batches (80 token rows = 5 MFMA tiles).
// LDS: QKV f16 [3][8][80][16], wave-private per head, 4-f16-chunk XOR swizzle
// (slot = chunk ^ ((row>>2)&3)).
// Phase1: QKV proj (swapped MFMA; full unroll so x loads pipeline deeply)
// Phase2: per-wave attention (fdot2 scores, packed-f16 PV); AO overwrites Q region.
//         NO barrier before phase2 -- all LDS traffic is wave-private.
// Phase3: O-proj (swapped MFMA -> nontemporal float4 stores). ONE __syncthreads total.
__global__ __launch_bounds__(512, 4)
void k_fused(const float* __restrict__ x, const float* __restrict__ bq,
             const float* __restrict__ bk, const float* __restrict__ bv,
             const float* __restrict__ bo, const float* __restrict__ pbias,
             float* __restrict__ out) {
    __shared__ __align__(16) f16 QKVs[3][8][80][16];

    const int tid  = threadIdx.x;
    const int w    = tid >> 6;      // wave = head
    const int lane = tid & 63;
    const int c    = lane & 15;
    const int g    = lane >> 4;
    const int base = blockIdx.x * 80;
    const int key_c = (c >> 2) & 3;

    // ---- register prefetch: QKV weight fragments, biases, pbias rows ----
    f16x8 wA[3][4];
#pragma unroll
    for (int ks = 0; ks < 4; ++ks) {
        wA[0][ks] = *(const f16x8*)&g_WT[0][w * 16 + c][ks * 32 + g * 8];
        wA[1][ks] = *(const f16x8*)&g_WT[1][w * 16 + c][ks * 32 + g * 8];
        wA[2][ks] = *(const f16x8*)&g_WT[2][w * 16 + c][ks * 32 + g * 8];
    }
    float4 bq4 = *(const float4*)&bq[w * 16 + g * 4];
    float4 bk4 = *(const float4*)&bk[w * 16 + g * 4];
    float4 bv4 = *(const float4*)&bv[w * 16 + g * 4];

    const int rowA = lane;                          // task A: rows 0..63
    const int b5A  = rowA / 5, qiA = rowA - b5A * 5;
    const int rowB = 64 + lane;                     // task B: rows 64..79 (lane<16)
    const int b5B  = rowB / 5, qiB = rowB - b5B * 5;
    float pbA[5], pbB[5];
#pragma unroll
    for (int j = 0; j < 5; ++j) {
        pbA[j] = pbias[w * 25 + qiA * 5 + j];
        pbB[j] = pbias[w * 25 + qiB * 5 + j];       // qiB in [0,4] -> always in-bounds
    }

    // ---- Phase 1: QKV projection (full unroll; loads hoist & pipeline) ----
#pragma unroll
    for (int t = 0; t < 5; ++t) {
        const float* xr = x + (size_t)(base + t * 16 + c) * 128;
        f32x4 qa = {0.f, 0.f, 0.f, 0.f}, ka = {0.f, 0.f, 0.f, 0.f}, va = {0.f, 0.f, 0.f, 0.f};
#pragma unroll
        for (int ks = 0; ks < 4; ++ks) {
            float4 u0 = *(const float4*)(xr + ks * 32 + g * 8);
            float4 u1 = *(const float4*)(xr + ks * 32 + g * 8 + 4);
            union { f16x8 v; f16x2 h[4]; } bx;
            bx.h[0] = pkh(u0.x, u0.y); bx.h[1] = pkh(u0.z, u0.w);
            bx.h[2] = pkh(u1.x, u1.y); bx.h[3] = pkh(u1.z, u1.w);
            qa = __builtin_amdgcn_mfma_f32_16x16x32_f16(wA[0][ks], bx.v, qa, 0, 0, 0);
            ka = __builtin_amdgcn_mfma_f32_16x16x32_f16(wA[1][ks], bx.v, ka, 0, 0, 0);
            va = __builtin_amdgcn_mfma_f32_16x16x32_f16(wA[2][ks], bx.v, va, 0, 0, 0);
        }
        int row  = t * 16 + c;               // token row; (row>>2)&3 == key_c
        int slot = g ^ key_c;                // swizzled chunk slot
        union { f16x4 v; f16x2 h[2]; } st;
        st.h[0] = pkh(qa[0] + bq4.x, qa[1] + bq4.y);
        st.h[1] = pkh(qa[2] + bq4.z, qa[3] + bq4.w);
        *(f16x4*)&QKVs[0][w][row][slot * 4] = st.v;
        st.h[0] = pkh(ka[0] + bk4.x, ka[1] + bk4.y);
        st.h[1] = pkh(ka[2] + bk4.z, ka[3] + bk4.w);
        *(f16x4*)&QKVs[1][w][row][slot * 4] = st.v;
        st.h[0] = pkh(va[0] + bv4.x, va[1] + bv4.y);
        st.h[1] = pkh(va[2] + bv4.z, va[3] + bv4.w);
        *(f16x4*)&QKVs[2][w][row][slot * 4] = st.v;
    }
    // NO __syncthreads here: QKVs[*][w] is wave-private (written and read by wave w only).

    // ---- Phase 2: attention (wave-private; head w, 80 rows over 64 lanes) ----
    auto attn = [&](int row, int b5, const float* pb) {
        const int key = (row >> 2) & 3;
        const int kr0 = b5 * 5;

        uint2 qw0 = *(const uint2*)&QKVs[0][w][row][(0 ^ key) * 4];
        uint2 qw1 = *(const uint2*)&QKVs[0][w][row][(1 ^ key) * 4];
        uint2 qw2 = *(const uint2*)&QKVs[0][w][row][(2 ^ key) * 4];
        uint2 qw3 = *(const uint2*)&QKVs[0][w][row][(3 ^ key) * 4];
        f16x2 q0 = bc2(qw0.x), q1 = bc2(qw0.y), q2 = bc2(qw1.x), q3 = bc2(qw1.y);
        f16x2 q4 = bc2(qw2.x), q5 = bc2(qw2.y), q6 = bc2(qw3.x), q7 = bc2(qw3.y);

        float s[5];
#pragma unroll
        for (int j = 0; j < 5; ++j) {
            int kr = kr0 + j;
            int kk = (kr >> 2) & 3;
            uint2 k0 = *(const uint2*)&QKVs[1][w][kr][(0 ^ kk) * 4];
            uint2 k1 = *(const uint2*)&QKVs[1][w][kr][(1 ^ kk) * 4];
            uint2 k2 = *(const uint2*)&QKVs[1][w][kr][(2 ^ kk) * 4];
            uint2 k3 = *(const uint2*)&QKVs[1][w][kr][(3 ^ kk) * 4];
            float d = 0.f;
            d = __builtin_amdgcn_fdot2(q0, bc2(k0.x), d, false);
            d = __builtin_amdgcn_fdot2(q1, bc2(k0.y), d, false);
            d = __builtin_amdgcn_fdot2(q2, bc2(k1.x), d, false);
            d = __builtin_amdgcn_fdot2(q3, bc2(k1.y), d, false);
            d = __builtin_amdgcn_fdot2(q4, bc2(k2.x), d, false);
            d = __builtin_amdgcn_fdot2(q5, bc2(k2.y), d, false);
            d = __builtin_amdgcn_fdot2(q6, bc2(k3.x), d, false);
            d = __builtin_amdgcn_fdot2(q7, bc2(k3.y), d, false);
            s[j] = d * 0.25f + pb[j];
        }
        float mx = fmaxf(fmaxf(fmaxf(s[0], s[1]), fmaxf(s[2], s[3])), s[4]);
        float psum = 0.f;
#pragma unroll
        for (int j = 0; j < 5; ++j) { s[j] = __expf(s[j] - mx); psum += s[j]; }
        float inv = 1.0f / psum;

        f16x2 o2[8];
#pragma unroll
        for (int i = 0; i < 8; ++i) { o2[i][0] = (f16)0.f; o2[i][1] = (f16)0.f; }
#pragma unroll
        for (int j = 0; j < 5; ++j) {
            int kr = kr0 + j;
            int kk = (kr >> 2) & 3;
            uint2 v0 = *(const uint2*)&QKVs[2][w][kr][(0 ^ kk) * 4];
            uint2 v1 = *(const uint2*)&QKVs[2][w][kr][(1 ^ kk) * 4];
            uint2 v2 = *(const uint2*)&QKVs[2][w][kr][(2 ^ kk) * 4];
            uint2 v3 = *(const uint2*)&QKVs[2][w][kr][(3 ^ kk) * 4];
            f16 pf = (f16)(s[j] * inv);
            f16x2 p2; p2[0] = pf; p2[1] = pf;
            o2[0] += p2 * bc2(v0.x); o2[1] += p2 * bc2(v0.y);
            o2[2] += p2 * bc2(v1.x); o2[3] += p2 * bc2(v1.y);
            o2[4] += p2 * bc2(v2.x); o2[5] += p2 * bc2(v2.y);
            o2[6] += p2 * bc2(v3.x); o2[7] += p2 * bc2(v3.y);
        }
        // AO overwrites Q region (wave-private; rows 64..79 never written by task A)
        union { f16x4 v; f16x2 h[2]; } st;
        st.h[0] = o2[0]; st.h[1] = o2[1]; *(f16x4*)&QKVs[0][w][row][(0 ^ key) * 4] = st.v;
        st.h[0] = o2[2]; st.h[1] = o2[3]; *(f16x4*)&QKVs[0][w][row][(1 ^ key) * 4] = st.v;
        st.h[0] = o2[4]; st.h[1] = o2[5]; *(f16x4*)&QKVs[0][w][row][(2 ^ key) * 4] = st.v;
        st.h[0] = o2[6]; st.h[1] = o2[7]; *(f16x4*)&QKVs[0][w][row][(3 ^ key) * 4] = st.v;
    };
    attn(rowA, b5A, pbA);
    if (lane < 16) attn(rowB, b5B, pbB);

    // ---- prefetch Wo fragments + bo while waiting at the barrier ----
    f16x8 wo[4];
#pragma unroll
    for (int ks = 0; ks < 4; ++ks)
        wo[ks] = *(const f16x8*)&g_WT[3][w * 16 + c][ks * 32 + g * 8];
    float4 bo4 = *(const float4*)&bo[w * 16 + g * 4];

    __syncthreads();   // the ONLY barrier: AO of all heads -> all waves

    // ---- Phase 3: output projection (wave w -> output cols w*16..w*16+15) ----
    const int hh_b = g >> 1;
    const int c0   = (g & 1) * 2;
#pragma unroll
    for (int t = 0; t < 5; ++t) {
        int row = t * 16 + c;                 // (row>>2)&3 == key_c
        f32x4 acc = {0.f, 0.f, 0.f, 0.f};
#pragma unroll
        for (int ks = 0; ks < 4; ++ks) {
            int hh = ks * 2 + hh_b;
            f16x4 lo = *(const f16x4*)&QKVs[0][hh][row][((c0 ^ key_c)) * 4];
            f16x4 hi = *(const f16x4*)&QKVs[0][hh][row][(((c0 + 1) ^ key_c)) * 4];
            acc = __builtin_amdgcn_mfma_f32_16x16x32_f16(wo[ks], cat8(lo, hi), acc, 0, 0, 0);
        }
        fltx4 r;
        r[0] = acc[0] + bo4.x; r[1] = acc[1] + bo4.y;
        r[2] = acc[2] + bo4.z; r[3] = acc[3] + bo4.w;
        __builtin_nontemporal_store(r, (fltx4*)&out[(size_t)(base + row) * 128 + w * 16 + g * 4]);
    }
}

extern "C" void kernel_launch(void* const* d_in, const int* in_sizes, int n_in,
                              void* d_out, int out_size, void* d_ws, size_t ws_size,
                              hipStream_t stream) {
    const float* x     = (const float*)d_in[0];
    const float* Wq    = (const float*)d_in[1];
    const float* bq    = (const float*)d_in[2];
    const float* Wk    = (const float*)d_in[3];
    const float* bk    = (const float*)d_in[4];
    const float* Wv    = (const float*)d_in[5];
    const float* bv    = (const float*)d_in[6];
    const float* Wo    = (const float*)d_in[7];
    const float* bo    = (const float*)d_in[8];
    const float* pbias = (const float*)d_in[9];
    float* out = (float*)d_out;

    k_wtrans<<<dim3(256), dim3(256), 0, stream>>>(Wq, Wk, Wv, Wo);
    k_fused<<<dim3(NB / 16), dim3(512), 0, stream>>>(x, bq, bk, bv, bo, pbias, out);
}